// Round 5
// baseline (295.214 us; speedup 1.0000x reference)
//
#include <hip/hip_runtime.h>

// Problem constants: B=8, N=2048, C=512, CR=64
typedef __attribute__((ext_vector_type(4))) float f32x4;
typedef __attribute__((ext_vector_type(4))) __bf16 bf16x4;
typedef __attribute__((ext_vector_type(8))) __bf16 bf16x8;
typedef __attribute__((ext_vector_type(8))) unsigned short u16x8;

// Native converts: gfx950 lowers fptrunc f32->bf16 to v_cvt_pk_bf16_f32.
__device__ __forceinline__ unsigned short f2bf(float f) {
  __bf16 h = (__bf16)f;
  return __builtin_bit_cast(unsigned short, h);
}
__device__ __forceinline__ u16x8 cvt8(float4 a, float4 b) {
  bf16x8 h = {(__bf16)a.x, (__bf16)a.y, (__bf16)a.z, (__bf16)a.w,
              (__bf16)b.x, (__bf16)b.y, (__bf16)b.z, (__bf16)b.w};
  return __builtin_bit_cast(u16x8, h);
}
__device__ __forceinline__ bf16x8 frag_at(const unsigned short* p) {
  return *reinterpret_cast<const bf16x8*>(p);
}
__device__ __forceinline__ f32x4 mfma16(bf16x8 a, bf16x8 b, f32x4 c) {
  return __builtin_amdgcn_mfma_f32_16x16x32_bf16(a, b, c, 0, 0, 0);
}

// ---------------- fused projections ---------------------------------------
// grid 640 x 512 thr. blocks [0,128): proj_kv (128-token x 128-o tiles);
// blocks [128,640): proj_q (128-o x 128-n tiles). Weights fp32->bf16 staged
// on the fly via v_cvt_pk. 8 waves: (wr = w>>2) 64-row half x (wc = w&3)
// 32-col strip; acc[4][2].
__global__ __launch_bounds__(512, 4) void proj_all_kernel(
    const float* __restrict__ x,
    const float* __restrict__ Wk, const float* __restrict__ bk,
    const float* __restrict__ Wv, const float* __restrict__ bv,
    const float* __restrict__ Wq, const float* __restrict__ bq,
    unsigned short* __restrict__ kbf, unsigned short* __restrict__ vtbf,
    unsigned short* __restrict__ qt) {
  __shared__ unsigned short As[128][72];
  __shared__ unsigned short Bs[128][72];
  const int t = threadIdx.x;
  const int w = t >> 6, lane = t & 63, lr = lane & 15, lg = lane >> 4;
  const int wr = w >> 2, wc = w & 3;
  const int srow = t >> 2, sq = t & 3;  // staging: 4 thr/row, 16 elems each

  f32x4 acc[4][2];
#pragma unroll
  for (int a = 0; a < 4; ++a)
#pragma unroll
    for (int c = 0; c < 2; ++c) acc[a][c] = (f32x4){0.f, 0.f, 0.f, 0.f};

  if (blockIdx.x < 128) {
    // ---------------- proj_kv: A = x tokens, B = [Wk;Wv] ----------------
    const int tok0 = blockIdx.x * 128;
    const float* wrow = (srow < 64) ? (Wk + (size_t)srow * 512)
                                    : (Wv + (size_t)(srow - 64) * 512);
    for (int kk = 0; kk < 8; ++kk) {
      const int k0 = kk * 64;
      {
        const float4* sa = reinterpret_cast<const float4*>(
            x + (size_t)(tok0 + srow) * 512 + k0 + sq * 16);
        float4 a0 = sa[0], a1 = sa[1], a2 = sa[2], a3 = sa[3];
        *reinterpret_cast<u16x8*>(&As[srow][sq * 16])     = cvt8(a0, a1);
        *reinterpret_cast<u16x8*>(&As[srow][sq * 16 + 8]) = cvt8(a2, a3);
        const float4* sb = reinterpret_cast<const float4*>(wrow + k0 + sq * 16);
        float4 b0 = sb[0], b1 = sb[1], b2 = sb[2], b3 = sb[3];
        *reinterpret_cast<u16x8*>(&Bs[srow][sq * 16])     = cvt8(b0, b1);
        *reinterpret_cast<u16x8*>(&Bs[srow][sq * 16 + 8]) = cvt8(b2, b3);
      }
      __syncthreads();
#pragma unroll
      for (int s = 0; s < 2; ++s) {
        bf16x8 bf0 = frag_at(&Bs[wc * 32 + lr][s * 32 + lg * 8]);
        bf16x8 bf1 = frag_at(&Bs[wc * 32 + 16 + lr][s * 32 + lg * 8]);
#pragma unroll
        for (int ab = 0; ab < 4; ++ab) {
          bf16x8 af = frag_at(&As[wr * 64 + ab * 16 + lr][s * 32 + lg * 8]);
          acc[ab][0] = mfma16(af, bf0, acc[ab][0]);
          acc[ab][1] = mfma16(af, bf1, acc[ab][1]);
        }
      }
      __syncthreads();
    }
#pragma unroll
    for (int nb = 0; nb < 2; ++nb) {
      const int o = wc * 32 + nb * 16 + lr;
      const float bias = (o < 64) ? bk[o] : bv[o - 64];
#pragma unroll
      for (int ab = 0; ab < 4; ++ab)
#pragma unroll
        for (int i = 0; i < 4; ++i) {
          const int token = tok0 + wr * 64 + ab * 16 + lg * 4 + i;
          const unsigned short hv = f2bf(acc[ab][nb][i] + bias);
          if (o < 64) kbf[(size_t)token * 64 + o] = hv;
          else        vtbf[(size_t)token * 64 + (o - 64)] = hv;
        }
    }
  } else {
    // ---------------- proj_q: A = Wq rows (o), B = x rows (n) ----------
    const int bi = blockIdx.x - 128;
    const int b = bi & 7, r = bi >> 3, ot = r >> 4, ntl = r & 15;
    const int o0 = ot * 128, n0 = ntl * 128;
    for (int kk = 0; kk < 8; ++kk) {
      const int k0 = kk * 64;
      {
        const float4* sa = reinterpret_cast<const float4*>(
            Wq + (size_t)(o0 + srow) * 512 + k0 + sq * 16);
        float4 a0 = sa[0], a1 = sa[1], a2 = sa[2], a3 = sa[3];
        *reinterpret_cast<u16x8*>(&As[srow][sq * 16])     = cvt8(a0, a1);
        *reinterpret_cast<u16x8*>(&As[srow][sq * 16 + 8]) = cvt8(a2, a3);
        const float4* sb = reinterpret_cast<const float4*>(
            x + ((size_t)b * 2048 + n0 + srow) * 512 + k0 + sq * 16);
        float4 b0 = sb[0], b1 = sb[1], b2 = sb[2], b3 = sb[3];
        *reinterpret_cast<u16x8*>(&Bs[srow][sq * 16])     = cvt8(b0, b1);
        *reinterpret_cast<u16x8*>(&Bs[srow][sq * 16 + 8]) = cvt8(b2, b3);
      }
      __syncthreads();
#pragma unroll
      for (int s = 0; s < 2; ++s) {
        bf16x8 bf0 = frag_at(&Bs[wc * 32 + lr][s * 32 + lg * 8]);
        bf16x8 bf1 = frag_at(&Bs[wc * 32 + 16 + lr][s * 32 + lg * 8]);
#pragma unroll
        for (int ab = 0; ab < 4; ++ab) {
          bf16x8 af = frag_at(&As[wr * 64 + ab * 16 + lr][s * 32 + lg * 8]);
          acc[ab][0] = mfma16(af, bf0, acc[ab][0]);
          acc[ab][1] = mfma16(af, bf1, acc[ab][1]);
        }
      }
      __syncthreads();
    }
#pragma unroll
    for (int ab = 0; ab < 4; ++ab)
#pragma unroll
      for (int i = 0; i < 4; ++i) {
        const int o = o0 + wr * 64 + ab * 16 + lg * 4 + i;
        const float bias = bq[o];
#pragma unroll
        for (int nb = 0; nb < 2; ++nb) {
          const int n = n0 + wc * 32 + nb * 16 + lr;
          qt[((size_t)b * 512 + o) * 2048 + n] = f2bf(acc[ab][nb][i] + bias);
        }
      }
  }
}

// ---------------- attention ------------------------------------------------
// Grid 1024 = 8 b x 32 mt x 4 ch; 256 thr (4 waves); 4 blocks/CU
// (__launch_bounds__(256,4) caps VGPR at 128 -> 16 waves/CU).
// Block: 64 m x 128 c quarter. Wave w: S for m rows [w*16,w*16+16) over the
// full 64-n tile (swapped mfma(K,vt) -> P lane-local per m=lr); PV c-range
// ch*128 + w*32 (qt read once per (b,mt) across the 4 ch blocks).
// P shared via double-buffered LDS with a RAW s_barrier + lgkmcnt(0)-only
// drain: global k/qt prefetches stay in flight across the barrier (no
// vmcnt(0) drain as __syncthreads would emit).
__global__ __launch_bounds__(256, 4) void attn_kernel(
    const float* __restrict__ x, const unsigned short* __restrict__ kbf,
    const unsigned short* __restrict__ vtbf, const unsigned short* __restrict__ qt,
    const float* __restrict__ g, float* __restrict__ out) {
  __shared__ unsigned short p_lds[2][64][72];  // 18.4 KB
  __shared__ float dsum_lds[64];
  const int t = threadIdx.x;
  const int b = blockIdx.x & 7;  // XCD-local batch
  const int rest = blockIdx.x >> 3;
  const int mt = rest >> 2, ch = rest & 3;
  const int m0 = mt * 64;
  const int w = t >> 6, lane = t & 63, lr = lane & 15, lg = lane >> 4;

  const unsigned short* kbase = kbf + (size_t)b * 2048 * 64;
  const unsigned short* vrow =
      vtbf + (size_t)(b * 2048 + m0 + w * 16 + lr) * 64;
  const bf16x8 qf0 = frag_at(vrow + lg * 8);
  const bf16x8 qf1 = frag_at(vrow + 32 + lg * 8);
  const unsigned short* qtb =
      qt + ((size_t)b * 512 + ch * 128 + w * 32) * 2048;

  f32x4 acc[4][2];  // [mc][cb]: 64 m x 32 c per wave
#pragma unroll
  for (int mc = 0; mc < 4; ++mc)
#pragma unroll
    for (int cb = 0; cb < 2; ++cb) acc[mc][cb] = (f32x4){0.f, 0.f, 0.f, 0.f};
  float dsum = 0.f;

  // prologue: tile-0 operand prefetch
  bf16x8 kf[4][2], bfr[2][2];
#pragma unroll
  for (int nb = 0; nb < 4; ++nb) {
    const unsigned short* krow = kbase + (size_t)(nb * 16 + lr) * 64;
    kf[nb][0] = frag_at(krow + lg * 8);
    kf[nb][1] = frag_at(krow + 32 + lg * 8);
  }
#pragma unroll
  for (int cb = 0; cb < 2; ++cb) {
    const unsigned short* qrow = qtb + (size_t)(cb * 16 + lr) * 2048;
    bfr[cb][0] = frag_at(qrow + lg * 8);
    bfr[cb][1] = frag_at(qrow + 32 + lg * 8);
  }

  for (int nt = 0; nt < 32; ++nt) {
    const int buf = nt & 1;

    // S (swapped): lane holds P[m = w*16+lr][n = nb*16 + lg*4 + i]
    f32x4 sacc[4];
#pragma unroll
    for (int nb = 0; nb < 4; ++nb) {
      sacc[nb] = (f32x4){0.f, 0.f, 0.f, 0.f};
      sacc[nb] = mfma16(kf[nb][0], qf0, sacc[nb]);
      sacc[nb] = mfma16(kf[nb][1], qf1, sacc[nb]);
    }
    // prefetch next tile's k-frags (affine addr; in flight across barrier)
    if (nt + 1 < 32) {
#pragma unroll
      for (int nb = 0; nb < 4; ++nb) {
        const unsigned short* krow =
            kbase + (size_t)((nt + 1) * 64 + nb * 16 + lr) * 64;
        kf[nb][0] = frag_at(krow + lg * 8);
        kf[nb][1] = frag_at(krow + 32 + lg * 8);
      }
    }
    // exp + lane-local denominator + native cvt_pk pack + LDS write
#pragma unroll
    for (int nb = 0; nb < 4; ++nb) {
      float e0 = __expf(sacc[nb][0]);
      float e1 = __expf(sacc[nb][1]);
      float e2 = __expf(sacc[nb][2]);
      float e3 = __expf(sacc[nb][3]);
      dsum += (e0 + e1) + (e2 + e3);
      bf16x4 pk = {(__bf16)e0, (__bf16)e1, (__bf16)e2, (__bf16)e3};
      *reinterpret_cast<bf16x4*>(&p_lds[buf][w * 16 + lr][nb * 16 + lg * 4]) = pk;
    }
    // raw barrier: drain LDS writes only; global prefetches stay in flight
    asm volatile("s_waitcnt lgkmcnt(0)" ::: "memory");
    __builtin_amdgcn_s_barrier();
    asm volatile("" ::: "memory");

    // PV: acc[64m x 32c] += P . qt
#pragma unroll
    for (int mc = 0; mc < 4; ++mc) {
      bf16x8 pf0 = frag_at(&p_lds[buf][mc * 16 + lr][lg * 8]);
      bf16x8 pf1 = frag_at(&p_lds[buf][mc * 16 + lr][32 + lg * 8]);
#pragma unroll
      for (int cb = 0; cb < 2; ++cb) {
        acc[mc][cb] = mfma16(pf0, bfr[cb][0], acc[mc][cb]);
        acc[mc][cb] = mfma16(pf1, bfr[cb][1], acc[mc][cb]);
      }
    }
    // prefetch next tile's qt-frags (consumed after the NEXT barrier)
    if (nt + 1 < 32) {
#pragma unroll
      for (int cb = 0; cb < 2; ++cb) {
        const unsigned short* qrow =
            qtb + (size_t)(cb * 16 + lr) * 2048 + (nt + 1) * 64;
        bfr[cb][0] = frag_at(qrow + lg * 8);
        bfr[cb][1] = frag_at(qrow + 32 + lg * 8);
      }
    }
  }

  // denominator: lane holds partial for m = w*16+lr; combine lg groups
  dsum += __shfl_xor(dsum, 16);
  dsum += __shfl_xor(dsum, 32);
  if (lane < 16) dsum_lds[w * 16 + lane] = dsum;
  __syncthreads();

  const float gamma = g[0];
#pragma unroll
  for (int mc = 0; mc < 4; ++mc) {
#pragma unroll
    for (int i = 0; i < 4; ++i) {
      const int mrow = mc * 16 + lg * 4 + i;
      const float s = gamma / dsum_lds[mrow];
      const size_t base =
          ((size_t)b * 2048 + m0 + mrow) * 512 + ch * 128 + w * 32;
#pragma unroll
      for (int cb = 0; cb < 2; ++cb) {
        const size_t idx = base + cb * 16 + lr;
        out[idx] = acc[mc][cb][i] * s + x[idx];
      }
    }
  }
}

// ---------------- launcher ----------------
extern "C" void kernel_launch(void* const* d_in, const int* in_sizes, int n_in,
                              void* d_out, int out_size, void* d_ws, size_t ws_size,
                              hipStream_t stream) {
  const float* x  = (const float*)d_in[0];
  const float* Wk = (const float*)d_in[1];
  const float* bk = (const float*)d_in[2];
  const float* Wv = (const float*)d_in[3];
  const float* bv = (const float*)d_in[4];
  const float* Wq = (const float*)d_in[5];
  const float* bq = (const float*)d_in[6];
  const float* g  = (const float*)d_in[7];
  float* out = (float*)d_out;

  char* ws = (char*)d_ws;
  unsigned short* kbf  = (unsigned short*)(ws);            // 2 MB
  unsigned short* vtbf = (unsigned short*)(ws + 2097152);  // 2 MB
  unsigned short* qt   = (unsigned short*)(ws + 4194304);  // 16 MB

  hipLaunchKernelGGL(proj_all_kernel, dim3(640), dim3(512), 0, stream,
                     x, Wk, bk, Wv, bv, Wq, bq, kbf, vtbf, qt);
  hipLaunchKernelGGL(attn_kernel, dim3(1024), dim3(256), 0, stream,
                     x, kbf, vtbf, qt, g, out);
}

// Round 6
// 240.181 us; speedup vs baseline: 1.2291x; 1.2291x over previous
//
#include <hip/hip_runtime.h>

// Problem constants: B=8, N=2048, C=512, CR=64
typedef __attribute__((ext_vector_type(4))) float f32x4;
typedef __attribute__((ext_vector_type(4))) __bf16 bf16x4;
typedef __attribute__((ext_vector_type(8))) __bf16 bf16x8;
typedef __attribute__((ext_vector_type(8))) unsigned short u16x8;

// Native converts: fptrunc f32->bf16 lowers to v_cvt_pk_bf16_f32 on gfx950.
__device__ __forceinline__ unsigned short f2bf(float f) {
  __bf16 h = (__bf16)f;
  return __builtin_bit_cast(unsigned short, h);
}
__device__ __forceinline__ u16x8 cvt8(float4 a, float4 b) {
  bf16x8 h = {(__bf16)a.x, (__bf16)a.y, (__bf16)a.z, (__bf16)a.w,
              (__bf16)b.x, (__bf16)b.y, (__bf16)b.z, (__bf16)b.w};
  return __builtin_bit_cast(u16x8, h);
}
__device__ __forceinline__ bf16x8 frag_at(const unsigned short* p) {
  return *reinterpret_cast<const bf16x8*>(p);
}
__device__ __forceinline__ f32x4 mfma16(bf16x8 a, bf16x8 b, f32x4 c) {
  return __builtin_amdgcn_mfma_f32_16x16x32_bf16(a, b, c, 0, 0, 0);
}

// ---------------- fused projections ---------------------------------------
// grid 768 x 512 thr, __launch_bounds__(512,2) (VGPR cap 256 -> compiler
// keeps pipeline regs; LDS 36.9KB -> 2+ blocks/CU by LDS).
// blocks [0,256):   proj_kv, 64-token x 128-o tiles (o = [Wk;Wv] rows)
// blocks [256,768): proj_q,  128-o x 128-n tiles per batch (b = idx&7 ->
//                   same-XCD L2 reuse of the x n-tile across the 4 o-tiles)
__global__ __launch_bounds__(512, 2) void proj_kernel(
    const float* __restrict__ x,
    const float* __restrict__ Wk, const float* __restrict__ bk,
    const float* __restrict__ Wv, const float* __restrict__ bv,
    const float* __restrict__ Wq, const float* __restrict__ bq,
    unsigned short* __restrict__ kbf, unsigned short* __restrict__ vtbf,
    unsigned short* __restrict__ qt) {
  __shared__ unsigned short As[128][72];
  __shared__ unsigned short Bs[128][72];
  const int t = threadIdx.x;
  const int w = t >> 6, lane = t & 63, lr = lane & 15, lg = lane >> 4;

  if (blockIdx.x < 256) {
    // ---------------- proj_kv: 64 tokens x 128 o ----------------
    const int tok0 = blockIdx.x * 64;
    const int wt = w & 3, oh = w >> 2;  // wave: 16 tokens x 64 o
    f32x4 acc[4];
#pragma unroll
    for (int c = 0; c < 4; ++c) acc[c] = (f32x4){0.f, 0.f, 0.f, 0.f};
    const int arow = t >> 3, aq = t & 7;    // x: 8 thr/row, 8 elems
    const int brow = t >> 2, bq2 = t & 3;   // W: 4 thr/row, 16 elems
    const float* wrow = (brow < 64) ? Wk + (size_t)brow * 512
                                    : Wv + (size_t)(brow - 64) * 512;
    for (int kk = 0; kk < 8; ++kk) {
      const int k0 = kk * 64;
      {
        const float4* sa = reinterpret_cast<const float4*>(
            x + (size_t)(tok0 + arow) * 512 + k0 + aq * 8);
        float4 a0 = sa[0], a1 = sa[1];
        *reinterpret_cast<u16x8*>(&As[arow][aq * 8]) = cvt8(a0, a1);
        const float4* sb = reinterpret_cast<const float4*>(wrow + k0 + bq2 * 16);
        float4 b0 = sb[0], b1 = sb[1], b2 = sb[2], b3 = sb[3];
        *reinterpret_cast<u16x8*>(&Bs[brow][bq2 * 16])     = cvt8(b0, b1);
        *reinterpret_cast<u16x8*>(&Bs[brow][bq2 * 16 + 8]) = cvt8(b2, b3);
      }
      __syncthreads();
#pragma unroll
      for (int s = 0; s < 2; ++s) {
        bf16x8 af = frag_at(&As[wt * 16 + lr][s * 32 + lg * 8]);
#pragma unroll
        for (int cb = 0; cb < 4; ++cb) {
          bf16x8 bf = frag_at(&Bs[oh * 64 + cb * 16 + lr][s * 32 + lg * 8]);
          acc[cb] = mfma16(af, bf, acc[cb]);
        }
      }
      __syncthreads();
    }
#pragma unroll
    for (int cb = 0; cb < 4; ++cb) {
      const int o = oh * 64 + cb * 16 + lr;
      const float bias = (o < 64) ? bk[o] : bv[o - 64];
#pragma unroll
      for (int i = 0; i < 4; ++i) {
        const int token = tok0 + wt * 16 + lg * 4 + i;
        const unsigned short hv = f2bf(acc[cb][i] + bias);
        if (o < 64) kbf[(size_t)token * 64 + o] = hv;
        else        vtbf[(size_t)token * 64 + (o - 64)] = hv;
      }
    }
  } else {
    // ---------------- proj_q: 128 o x 128 n per batch ----------------
    const int bi = blockIdx.x - 256;
    const int b = bi & 7, r = bi >> 3, ot = r & 3, ntl = r >> 2;
    const int o0 = ot * 128, n0 = ntl * 128;
    const int wrh = w >> 2, wc = w & 3;  // wave: 64 o x 32 n
    f32x4 acc[4][2];
#pragma unroll
    for (int a = 0; a < 4; ++a)
#pragma unroll
      for (int c = 0; c < 2; ++c) acc[a][c] = (f32x4){0.f, 0.f, 0.f, 0.f};
    const int srow = t >> 2, sq = t & 3;  // 4 thr/row, 16 elems
    for (int kk = 0; kk < 8; ++kk) {
      const int k0 = kk * 64;
      {
        const float4* sa = reinterpret_cast<const float4*>(
            Wq + (size_t)(o0 + srow) * 512 + k0 + sq * 16);
        float4 a0 = sa[0], a1 = sa[1], a2 = sa[2], a3 = sa[3];
        *reinterpret_cast<u16x8*>(&As[srow][sq * 16])     = cvt8(a0, a1);
        *reinterpret_cast<u16x8*>(&As[srow][sq * 16 + 8]) = cvt8(a2, a3);
        const float4* sb = reinterpret_cast<const float4*>(
            x + ((size_t)b * 2048 + n0 + srow) * 512 + k0 + sq * 16);
        float4 b0 = sb[0], b1 = sb[1], b2 = sb[2], b3 = sb[3];
        *reinterpret_cast<u16x8*>(&Bs[srow][sq * 16])     = cvt8(b0, b1);
        *reinterpret_cast<u16x8*>(&Bs[srow][sq * 16 + 8]) = cvt8(b2, b3);
      }
      __syncthreads();
#pragma unroll
      for (int s = 0; s < 2; ++s) {
        bf16x8 bf0 = frag_at(&Bs[wc * 32 + lr][s * 32 + lg * 8]);
        bf16x8 bf1 = frag_at(&Bs[wc * 32 + 16 + lr][s * 32 + lg * 8]);
#pragma unroll
        for (int ab = 0; ab < 4; ++ab) {
          bf16x8 af = frag_at(&As[wrh * 64 + ab * 16 + lr][s * 32 + lg * 8]);
          acc[ab][0] = mfma16(af, bf0, acc[ab][0]);
          acc[ab][1] = mfma16(af, bf1, acc[ab][1]);
        }
      }
      __syncthreads();
    }
#pragma unroll
    for (int ab = 0; ab < 4; ++ab)
#pragma unroll
      for (int i = 0; i < 4; ++i) {
        const int o = o0 + wrh * 64 + ab * 16 + lg * 4 + i;
        const float bias = bq[o];
#pragma unroll
        for (int nb = 0; nb < 2; ++nb) {
          const int n = n0 + wc * 32 + nb * 16 + lr;
          qt[((size_t)b * 512 + o) * 2048 + n] = f2bf(acc[ab][nb][i] + bias);
        }
      }
  }
}

// ---------------- attention ------------------------------------------------
// R4 geometry: grid 512 = 8b x 32mt x 2ch; 256 thr (4 waves); 2 blocks/CU.
// __launch_bounds__(256,2): VGPR cap 256 -> prefetch regs stay live (the
// (256,4) cap in R5 demoted them -> serial loads).
// Wave w: S for m rows [w*16,w*16+16) over the full 64-n tile (swapped
// mfma(K,vt) -> P lane-local per m=lr); PV c-range ch*256 + w*64 (qt read
// once per block). P shared via double-buffered LDS.
// Barrier = s_waitcnt lgkmcnt(0) + raw s_barrier + sched_barrier(0):
// drains P ds_writes (and prior PV ds_reads -> double-buffer safe) but
// leaves the 24 global prefetch loads in flight across the barrier.
__global__ __launch_bounds__(256, 2) void attn_kernel(
    const float* __restrict__ x, const unsigned short* __restrict__ kbf,
    const unsigned short* __restrict__ vtbf, const unsigned short* __restrict__ qt,
    const float* __restrict__ g, float* __restrict__ out) {
  __shared__ unsigned short p_lds[2][64][72];  // 18.4 KB
  __shared__ float dsum_lds[64];
  const int t = threadIdx.x;
  const int b = blockIdx.x & 7;  // XCD-local batch
  const int rest = blockIdx.x >> 3;
  const int mt = rest >> 1, ch = rest & 1;
  const int m0 = mt * 64;
  const int w = t >> 6, lane = t & 63, lr = lane & 15, lg = lane >> 4;

  const unsigned short* kbase = kbf + (size_t)b * 2048 * 64;
  const unsigned short* vrow =
      vtbf + (size_t)(b * 2048 + m0 + w * 16 + lr) * 64;
  const bf16x8 qf0 = frag_at(vrow + lg * 8);
  const bf16x8 qf1 = frag_at(vrow + 32 + lg * 8);
  const unsigned short* qtb =
      qt + ((size_t)b * 512 + ch * 256 + w * 64) * 2048;

  f32x4 acc[4][4];  // [mc][cb]: 64 m x 64 c per wave
#pragma unroll
  for (int mc = 0; mc < 4; ++mc)
#pragma unroll
    for (int cb = 0; cb < 4; ++cb) acc[mc][cb] = (f32x4){0.f, 0.f, 0.f, 0.f};
  float dsum = 0.f;

  // prologue: tile-0 operand prefetch
  bf16x8 kf[4][2], bfr[4][2];
#pragma unroll
  for (int nb = 0; nb < 4; ++nb) {
    const unsigned short* krow = kbase + (size_t)(nb * 16 + lr) * 64;
    kf[nb][0] = frag_at(krow + lg * 8);
    kf[nb][1] = frag_at(krow + 32 + lg * 8);
  }
#pragma unroll
  for (int cb = 0; cb < 4; ++cb) {
    const unsigned short* qrow = qtb + (size_t)(cb * 16 + lr) * 2048;
    bfr[cb][0] = frag_at(qrow + lg * 8);
    bfr[cb][1] = frag_at(qrow + 32 + lg * 8);
  }

  for (int nt = 0; nt < 32; ++nt) {
    const int buf = nt & 1;

    // S (swapped): lane holds P[m = w*16+lr][n = nb*16 + lg*4 + i]
    f32x4 sacc[4];
#pragma unroll
    for (int nb = 0; nb < 4; ++nb) {
      sacc[nb] = (f32x4){0.f, 0.f, 0.f, 0.f};
      sacc[nb] = mfma16(kf[nb][0], qf0, sacc[nb]);
      sacc[nb] = mfma16(kf[nb][1], qf1, sacc[nb]);
    }
    // prefetch next tile's k-frags (stay in flight across the barrier)
    if (nt + 1 < 32) {
#pragma unroll
      for (int nb = 0; nb < 4; ++nb) {
        const unsigned short* krow =
            kbase + (size_t)((nt + 1) * 64 + nb * 16 + lr) * 64;
        kf[nb][0] = frag_at(krow + lg * 8);
        kf[nb][1] = frag_at(krow + 32 + lg * 8);
      }
    }
    // exp + lane-local denominator + cvt_pk pack + LDS write ([m][n])
#pragma unroll
    for (int nb = 0; nb < 4; ++nb) {
      float e0 = __expf(sacc[nb][0]);
      float e1 = __expf(sacc[nb][1]);
      float e2 = __expf(sacc[nb][2]);
      float e3 = __expf(sacc[nb][3]);
      dsum += (e0 + e1) + (e2 + e3);
      bf16x4 pk = {(__bf16)e0, (__bf16)e1, (__bf16)e2, (__bf16)e3};
      *reinterpret_cast<bf16x4*>(&p_lds[buf][w * 16 + lr][nb * 16 + lg * 4]) = pk;
    }
    // raw barrier: drain DS ops only; global prefetches stay in flight
    asm volatile("s_waitcnt lgkmcnt(0)" ::: "memory");
    __builtin_amdgcn_s_barrier();
    __builtin_amdgcn_sched_barrier(0);

    // PV: acc[64m x 64c] += P . qt
    __builtin_amdgcn_s_setprio(1);
#pragma unroll
    for (int mc = 0; mc < 4; ++mc) {
      bf16x8 pf0 = frag_at(&p_lds[buf][mc * 16 + lr][lg * 8]);
      bf16x8 pf1 = frag_at(&p_lds[buf][mc * 16 + lr][32 + lg * 8]);
#pragma unroll
      for (int cb = 0; cb < 4; ++cb) {
        acc[mc][cb] = mfma16(pf0, bfr[cb][0], acc[mc][cb]);
        acc[mc][cb] = mfma16(pf1, bfr[cb][1], acc[mc][cb]);
      }
    }
    __builtin_amdgcn_s_setprio(0);
    // prefetch next tile's qt-frags (consumed after the NEXT barrier)
    if (nt + 1 < 32) {
#pragma unroll
      for (int cb = 0; cb < 4; ++cb) {
        const unsigned short* qrow =
            qtb + (size_t)(cb * 16 + lr) * 2048 + (nt + 1) * 64;
        bfr[cb][0] = frag_at(qrow + lg * 8);
        bfr[cb][1] = frag_at(qrow + 32 + lg * 8);
      }
    }
  }

  // denominator: lane holds partial for m = w*16+lr; combine lg groups
  dsum += __shfl_xor(dsum, 16);
  dsum += __shfl_xor(dsum, 32);
  if (lane < 16) dsum_lds[w * 16 + lane] = dsum;
  __syncthreads();

  const float gamma = g[0];
#pragma unroll
  for (int mc = 0; mc < 4; ++mc) {
#pragma unroll
    for (int i = 0; i < 4; ++i) {
      const int mrow = mc * 16 + lg * 4 + i;
      const float s = gamma / dsum_lds[mrow];
      const size_t base =
          ((size_t)b * 2048 + m0 + mrow) * 512 + ch * 256 + w * 64;
#pragma unroll
      for (int cb = 0; cb < 4; ++cb) {
        const size_t idx = base + cb * 16 + lr;
        out[idx] = acc[mc][cb][i] * s + x[idx];
      }
    }
  }
}

// ---------------- launcher ----------------
extern "C" void kernel_launch(void* const* d_in, const int* in_sizes, int n_in,
                              void* d_out, int out_size, void* d_ws, size_t ws_size,
                              hipStream_t stream) {
  const float* x  = (const float*)d_in[0];
  const float* Wk = (const float*)d_in[1];
  const float* bk = (const float*)d_in[2];
  const float* Wv = (const float*)d_in[3];
  const float* bv = (const float*)d_in[4];
  const float* Wq = (const float*)d_in[5];
  const float* bq = (const float*)d_in[6];
  const float* g  = (const float*)d_in[7];
  float* out = (float*)d_out;

  char* ws = (char*)d_ws;
  unsigned short* kbf  = (unsigned short*)(ws);            // 2 MB
  unsigned short* vtbf = (unsigned short*)(ws + 2097152);  // 2 MB
  unsigned short* qt   = (unsigned short*)(ws + 4194304);  // 16 MB

  hipLaunchKernelGGL(proj_kernel, dim3(768), dim3(512), 0, stream,
                     x, Wk, bk, Wv, bv, Wq, bq, kbf, vtbf, qt);
  hipLaunchKernelGGL(attn_kernel, dim3(512), dim3(256), 0, stream,
                     x, kbf, vtbf, qt, g, out);
}